// Round 1
// baseline (4385.049 us; speedup 1.0000x reference)
//
#include <hip/hip_runtime.h>
#include <stdint.h>

#define NBOX 1024
#define BLK  256

// ---------- bit-exact IoU (matches numpy f32 op-for-op; _rn blocks FMA contraction) ----------
__device__ __forceinline__ float iou_pair(const float4 lb, float larea,
                                          const float4 pb, float parea) {
    float ix1 = fmaxf(lb.x, pb.x);            // min_xy = max(a[:2], b[:2])
    float iy1 = fmaxf(lb.y, pb.y);
    float ix2 = fminf(lb.z, pb.z);            // max_xy = min(a[2:], b[2:])
    float iy2 = fminf(lb.w, pb.w);
    float w = fmaxf(__fsub_rn(ix2, ix1), 0.0f);
    float h = fmaxf(__fsub_rn(iy2, iy1), 0.0f);
    float inter = __fmul_rn(w, h);
    float denom = __fsub_rn(__fadd_rn(larea, parea), inter); // (area_a + area_b) - inter
    return inter / denom;                     // IEEE div (no fast-math in harness flags)
}

__device__ __forceinline__ unsigned long long umax64(unsigned long long a, unsigned long long b) {
    return a > b ? a : b;
}

__device__ __forceinline__ unsigned long long shflx64(unsigned long long v, int mask) {
    unsigned lo = __shfl_xor((unsigned)(v & 0xffffffffull), mask, 64);
    unsigned hi = __shfl_xor((unsigned)(v >> 32), mask, 64);
    return (((unsigned long long)hi) << 32) | lo;
}

// ---------- kernel 1: initial per-row (max, argcol-last) over all columns ----------
// one wave per row; lane j handles cols lane + 64*j (ascending per lane)
__global__ void init_rowmax(const float* __restrict__ labels,
                            const float* __restrict__ preds,
                            unsigned long long* __restrict__ key_ws,
                            unsigned short* __restrict__ col_ws) {
    const int b = blockIdx.x;
    const int lane = threadIdx.x;  // 0..63
    float4 lb = ((const float4*)labels)[b];
    float larea = __fmul_rn(__fsub_rn(lb.z, lb.x), __fsub_rn(lb.w, lb.y));
    float bv = -1.0f; int bc = 0;
    #pragma unroll 4
    for (int j = 0; j < 16; ++j) {
        int c = lane + (j << 6);
        float4 pb = ((const float4*)preds)[c];
        float parea = __fmul_rn(__fsub_rn(pb.z, pb.x), __fsub_rn(pb.w, pb.y));
        float v = iou_pair(lb, larea, pb, parea);
        if (v > bv || (v == bv && c > bc)) { bv = v; bc = c; }
    }
    // wave reduce, lexicographic (val, then larger col)
    for (int off = 32; off > 0; off >>= 1) {
        float ov = __shfl_xor(bv, off, 64);
        int   oc = __shfl_xor(bc, off, 64);
        if (ov > bv || (ov == bv && oc > bc)) { bv = ov; bc = oc; }
    }
    if (lane == 0) {
        key_ws[b] = ((unsigned long long)__float_as_uint(bv) << 11) |
                    ((unsigned)b << 1) | 1ull;
        col_ws[b] = (unsigned short)bc;
    }
}

// ---------- kernel 2: single-block sequential greedy + final L1 loss ----------
__global__ void __launch_bounds__(BLK, 1)
greedy_kernel(const float* __restrict__ preds,
              const float* __restrict__ labels,
              const unsigned long long* __restrict__ key_ws,
              const unsigned short* __restrict__ col_ws,
              float* __restrict__ out) {
    __shared__ unsigned long long key[NBOX];   // (f32bits<<11)|(row<<1)|1 ; 0 == seen
    __shared__ unsigned short    colv[NBOX];   // row's argmax column (last tie)
    __shared__ int               perm[NBOX];
    __shared__ unsigned char     seen[NBOX];
    __shared__ unsigned short    list[NBOX];   // rows to rescan this step
    __shared__ float4            pred4[NBOX];
    __shared__ float4            lab4[NBOX];
    __shared__ float             parea_s[NBOX];
    __shared__ unsigned long long part[4];
    __shared__ float             fpart[4];
    __shared__ int               listn;

    const int t    = threadIdx.x;
    const int lane = t & 63;
    const int wid  = t >> 6;

    for (int k = 0; k < 4; ++k) {
        int i = t + k * BLK;
        perm[i] = i;
        seen[i] = 0;
        float4 p = ((const float4*)preds)[i];
        pred4[i] = p;
        lab4[i]  = ((const float4*)labels)[i];
        parea_s[i] = __fmul_rn(__fsub_rn(p.z, p.x), __fsub_rn(p.w, p.y));
        if (key_ws) { key[i] = key_ws[i]; colv[i] = col_ws[i]; }
    }
    if (t == 0) listn = 0;
    __syncthreads();

    // rescan one row over currently-valid columns; one wave per call
    auto scan_row = [&](int row, int p) {
        float4 lb = lab4[p];
        float larea = __fmul_rn(__fsub_rn(lb.z, lb.x), __fsub_rn(lb.w, lb.y));
        float bv = -1.0f; int bc = 0;
        #pragma unroll 4
        for (int j = 0; j < 16; ++j) {
            int cc = lane + (j << 6);
            if (!seen[cc]) {
                float v = iou_pair(lb, larea, pred4[cc], parea_s[cc]);
                if (v > bv || (v == bv && cc > bc)) { bv = v; bc = cc; }
            }
        }
        for (int off = 32; off > 0; off >>= 1) {
            float ov = __shfl_xor(bv, off, 64);
            int   oc = __shfl_xor(bc, off, 64);
            if (ov > bv || (ov == bv && oc > bc)) { bv = ov; bc = oc; }
        }
        if (lane == 0) {
            key[row]  = ((unsigned long long)__float_as_uint(bv) << 11) |
                        ((unsigned)row << 1) | 1ull;
            colv[row] = (unsigned short)bc;
        }
    };

    if (!key_ws) {  // ws too small: compute initial row maxes in-kernel (seen[] all zero)
        for (int row = wid; row < NBOX; row += 4) scan_row(row, row);
        __syncthreads();
    }

    for (int step = 0; step < NBOX; ++step) {
        // ---- pick: global max key (val, then larger row) ----
        unsigned long long km = umax64(umax64(key[t], key[t + 256]),
                                       umax64(key[t + 512], key[t + 768]));
        for (int off = 32; off > 0; off >>= 1) km = umax64(km, shflx64(km, off));
        if (lane == 0) part[wid] = km;
        __syncthreads();                                   // B1
        unsigned long long kb = umax64(umax64(part[0], part[1]),
                                       umax64(part[2], part[3]));
        if ((kb >> 11) == 0ull) break;   // max IoU == 0.0 -> all remaining picks are
                                         // (i,i) no-op swaps; perm is final
        const int r = (int)((kb >> 1) & 1023);
        const int c = (int)colv[r];

        if (t == 0) {
            listn = 0;
            int pr = perm[r], pc = perm[c];
            perm[r] = pc; perm[c] = pr;
            seen[c] = 1;
            key[c] = 0;
            if (r != c) { list[0] = (unsigned short)r; listn = 1; }  // row r content changed
        }
        __syncthreads();                                   // B2

        // ---- rows whose stored argmax column just got removed ----
        for (int k = 0; k < 4; ++k) {
            int row = t + k * BLK;
            if (row != r && (int)colv[row] == c && !seen[row]) {
                int idx = atomicAdd(&listn, 1);
                list[idx] = (unsigned short)row;
            }
        }
        __syncthreads();                                   // B3

        const int n = listn;
        for (int base = 0; base < n; base += 4) {
            int li = base + wid;
            if (li < n) {
                int row = list[li];
                scan_row(row, perm[row]);
            }
        }
        __syncthreads();                                   // B4
    }

    // ---- loss = mean |labels[perm] - predictions| ----
    __syncthreads();
    float sum = 0.0f;
    for (int k = 0; k < 4; ++k) {
        int i = t + k * BLK;
        float4 lb = lab4[perm[i]];
        float4 pr = pred4[i];
        sum += fabsf(lb.x - pr.x) + fabsf(lb.y - pr.y) +
               fabsf(lb.z - pr.z) + fabsf(lb.w - pr.w);
    }
    for (int off = 32; off > 0; off >>= 1) sum += __shfl_xor(sum, off, 64);
    if (lane == 0) fpart[wid] = sum;
    __syncthreads();
    if (t == 0) out[0] = (fpart[0] + fpart[1] + fpart[2] + fpart[3]) * (1.0f / 4096.0f);
}

extern "C" void kernel_launch(void* const* d_in, const int* in_sizes, int n_in,
                              void* d_out, int out_size, void* d_ws, size_t ws_size,
                              hipStream_t stream) {
    const float* preds  = (const float*)d_in[0];   // predictions [1024,4]
    const float* labels = (const float*)d_in[1];   // labels      [1024,4]
    // d_in[2] (scores) is unused by the reference loss
    float* out = (float*)d_out;

    const size_t need = NBOX * sizeof(unsigned long long) + NBOX * sizeof(unsigned short);
    if (d_ws && ws_size >= need) {
        unsigned long long* key_ws = (unsigned long long*)d_ws;
        unsigned short*     col_ws = (unsigned short*)((char*)d_ws + NBOX * sizeof(unsigned long long));
        init_rowmax<<<NBOX, 64, 0, stream>>>(labels, preds, key_ws, col_ws);
        greedy_kernel<<<1, BLK, 0, stream>>>(preds, labels, key_ws, col_ws, out);
    } else {
        greedy_kernel<<<1, BLK, 0, stream>>>(preds, labels, nullptr, nullptr, out);
    }
}